// Round 2
// baseline (56.317 us; speedup 1.0000x reference)
//
#include <hip/hip_runtime.h>

// ContrastiveLoss: B=8192 rows, D=4096 fp32 features.
// Kernel 1: one 64-lane wave per row -> three dot products -> per-row loss in d_ws.
// Kernel 2: deterministic single-block reduction -> mean -> d_out[0].
//
// NOTE: target arrives as int32 (JAX x32 default; harness passes integer ->
// const int*), NOT int64 as the reference dtype string suggests.

#define WAVE 64
#define BLOCK 256
#define WAVES_PER_BLOCK (BLOCK / WAVE)

__global__ __launch_bounds__(BLOCK) void contrastive_row_loss(
    const float* __restrict__ o1,
    const float* __restrict__ o2,
    const int* __restrict__ target,
    float* __restrict__ row_loss,
    int B, int D) {
    const int wave = threadIdx.x >> 6;      // 0..3
    const int lane = threadIdx.x & 63;
    const int row  = blockIdx.x * WAVES_PER_BLOCK + wave;
    if (row >= B) return;

    const float4* __restrict__ p1 =
        reinterpret_cast<const float4*>(o1 + (size_t)row * D);
    const float4* __restrict__ p2 =
        reinterpret_cast<const float4*>(o2 + (size_t)row * D);
    const int nvec = D >> 2;                // 1024 float4 per row

    float dot = 0.0f, s1 = 0.0f, s2 = 0.0f;
    // Coalesced: lane i reads float4 index k*64 + i.
    for (int k = lane; k < nvec; k += WAVE) {
        float4 a = p1[k];
        float4 b = p2[k];
        dot += a.x * b.x + a.y * b.y + a.z * b.z + a.w * b.w;
        s1  += a.x * a.x + a.y * a.y + a.z * a.z + a.w * a.w;
        s2  += b.x * b.x + b.y * b.y + b.z * b.z + b.w * b.w;
    }

    // Wave-wide (64-lane) reduction.
    #pragma unroll
    for (int off = 32; off > 0; off >>= 1) {
        dot += __shfl_down(dot, off, WAVE);
        s1  += __shfl_down(s1,  off, WAVE);
        s2  += __shfl_down(s2,  off, WAVE);
    }

    if (lane == 0) {
        // cos = dot / (||a|| * ||b||); dist = 0.5*(1 - cos)
        float cosv = dot / (sqrtf(s1) * sqrtf(s2));
        float dist = 0.5f * (1.0f - cosv);
        int t = target[row];
        float loss;
        if (t != 0) {
            loss = 0.5f * dist;
        } else {
            float h = fmaxf(0.0f, 1.0f - sqrtf(dist + 1e-9f));
            loss = 0.5f * h * h;
        }
        row_loss[row] = loss;
    }
}

__global__ __launch_bounds__(BLOCK) void reduce_mean(
    const float* __restrict__ row_loss,
    float* __restrict__ out,
    int B) {
    // Single block; deterministic fixed-order reduction.
    float sum = 0.0f;
    for (int i = threadIdx.x; i < B; i += BLOCK) sum += row_loss[i];

    __shared__ float smem[WAVES_PER_BLOCK];
    #pragma unroll
    for (int off = 32; off > 0; off >>= 1) sum += __shfl_down(sum, off, WAVE);

    const int lane = threadIdx.x & 63;
    const int wave = threadIdx.x >> 6;
    if (lane == 0) smem[wave] = sum;
    __syncthreads();
    if (threadIdx.x == 0) {
        float tot = 0.0f;
        #pragma unroll
        for (int w = 0; w < WAVES_PER_BLOCK; ++w) tot += smem[w];
        out[0] = tot / (float)B;
    }
}

extern "C" void kernel_launch(void* const* d_in, const int* in_sizes, int n_in,
                              void* d_out, int out_size, void* d_ws, size_t ws_size,
                              hipStream_t stream) {
    const float* o1 = (const float*)d_in[0];
    const float* o2 = (const float*)d_in[1];
    const int* tgt = (const int*)d_in[2];

    const int B = in_sizes[2];            // 8192
    const int D = in_sizes[0] / B;        // 4096

    float* row_loss = (float*)d_ws;       // B floats = 32 KiB scratch
    float* out = (float*)d_out;

    const int grid = (B + WAVES_PER_BLOCK - 1) / WAVES_PER_BLOCK;
    contrastive_row_loss<<<grid, BLOCK, 0, stream>>>(o1, o2, tgt, row_loss, B, D);
    reduce_mean<<<1, BLOCK, 0, stream>>>(row_loss, out, B);
}

// Round 3
// 48.000 us; speedup vs baseline: 1.1733x; 1.1733x over previous
//
#include <hip/hip_runtime.h>

// ContrastiveLoss: B=8192 rows, D=4096 fp32 features.
// Kernel 1: one 64-lane wave per row; 4x-unrolled float4 loads (8 independent
//           loads in flight per lane) -> three dot products -> per-row loss.
// Kernel 2: deterministic single-block reduction -> mean -> d_out[0].
//
// target arrives as int32 (JAX x32 default; harness passes integer -> const int*).

#define WAVE 64
#define BLOCK 256
#define WAVES_PER_BLOCK (BLOCK / WAVE)

__global__ __launch_bounds__(BLOCK) void contrastive_row_loss(
    const float* __restrict__ o1,
    const float* __restrict__ o2,
    const int* __restrict__ target,
    float* __restrict__ row_loss,
    int B, int D) {
    const int wave = threadIdx.x >> 6;      // 0..3
    const int lane = threadIdx.x & 63;
    const int row  = blockIdx.x * WAVES_PER_BLOCK + wave;
    if (row >= B) return;

    const float4* __restrict__ p1 =
        reinterpret_cast<const float4*>(o1 + (size_t)row * D);
    const float4* __restrict__ p2 =
        reinterpret_cast<const float4*>(o2 + (size_t)row * D);
    // nvec = D/4 = 1024 float4 per row; 16 per lane; unroll 4 -> 4 outer iters.
    const int nvec = D >> 2;

    float dot0 = 0.f, dot1 = 0.f, dot2 = 0.f, dot3 = 0.f;
    float s1_0 = 0.f, s1_1 = 0.f, s1_2 = 0.f, s1_3 = 0.f;
    float s2_0 = 0.f, s2_1 = 0.f, s2_2 = 0.f, s2_3 = 0.f;

    for (int base = lane; base < nvec; base += WAVE * 4) {
        // 8 independent loads issued before any use.
        float4 a0 = p1[base];
        float4 a1 = p1[base + WAVE];
        float4 a2 = p1[base + WAVE * 2];
        float4 a3 = p1[base + WAVE * 3];
        float4 b0 = p2[base];
        float4 b1 = p2[base + WAVE];
        float4 b2 = p2[base + WAVE * 2];
        float4 b3 = p2[base + WAVE * 3];

        dot0 += a0.x * b0.x + a0.y * b0.y + a0.z * b0.z + a0.w * b0.w;
        s1_0 += a0.x * a0.x + a0.y * a0.y + a0.z * a0.z + a0.w * a0.w;
        s2_0 += b0.x * b0.x + b0.y * b0.y + b0.z * b0.z + b0.w * b0.w;

        dot1 += a1.x * b1.x + a1.y * b1.y + a1.z * b1.z + a1.w * b1.w;
        s1_1 += a1.x * a1.x + a1.y * a1.y + a1.z * a1.z + a1.w * a1.w;
        s2_1 += b1.x * b1.x + b1.y * b1.y + b1.z * b1.z + b1.w * b1.w;

        dot2 += a2.x * b2.x + a2.y * b2.y + a2.z * b2.z + a2.w * b2.w;
        s1_2 += a2.x * a2.x + a2.y * a2.y + a2.z * a2.z + a2.w * a2.w;
        s2_2 += b2.x * b2.x + b2.y * b2.y + b2.z * b2.z + b2.w * b2.w;

        dot3 += a3.x * b3.x + a3.y * b3.y + a3.z * b3.z + a3.w * b3.w;
        s1_3 += a3.x * a3.x + a3.y * a3.y + a3.z * a3.z + a3.w * a3.w;
        s2_3 += b3.x * b3.x + b3.y * b3.y + b3.z * b3.z + b3.w * b3.w;
    }

    float dot = (dot0 + dot1) + (dot2 + dot3);
    float s1  = (s1_0 + s1_1) + (s1_2 + s1_3);
    float s2  = (s2_0 + s2_1) + (s2_2 + s2_3);

    #pragma unroll
    for (int off = 32; off > 0; off >>= 1) {
        dot += __shfl_down(dot, off, WAVE);
        s1  += __shfl_down(s1,  off, WAVE);
        s2  += __shfl_down(s2,  off, WAVE);
    }

    if (lane == 0) {
        float cosv = dot / (sqrtf(s1) * sqrtf(s2));
        float dist = 0.5f * (1.0f - cosv);
        int t = target[row];
        float loss;
        if (t != 0) {
            loss = 0.5f * dist;
        } else {
            float h = fmaxf(0.0f, 1.0f - sqrtf(dist + 1e-9f));
            loss = 0.5f * h * h;
        }
        row_loss[row] = loss;
    }
}

__global__ __launch_bounds__(BLOCK) void reduce_mean(
    const float* __restrict__ row_loss,
    float* __restrict__ out,
    int B) {
    // Single block; deterministic fixed-order reduction; float4 loads.
    const float4* p = reinterpret_cast<const float4*>(row_loss);
    const int nvec = B >> 2;  // 2048
    float sum = 0.0f;
    for (int i = threadIdx.x; i < nvec; i += BLOCK) {
        float4 v = p[i];
        sum += (v.x + v.y) + (v.z + v.w);
    }

    __shared__ float smem[WAVES_PER_BLOCK];
    #pragma unroll
    for (int off = 32; off > 0; off >>= 1) sum += __shfl_down(sum, off, WAVE);

    const int lane = threadIdx.x & 63;
    const int wave = threadIdx.x >> 6;
    if (lane == 0) smem[wave] = sum;
    __syncthreads();
    if (threadIdx.x == 0) {
        float tot = 0.0f;
        #pragma unroll
        for (int w = 0; w < WAVES_PER_BLOCK; ++w) tot += smem[w];
        out[0] = tot / (float)B;
    }
}

extern "C" void kernel_launch(void* const* d_in, const int* in_sizes, int n_in,
                              void* d_out, int out_size, void* d_ws, size_t ws_size,
                              hipStream_t stream) {
    const float* o1 = (const float*)d_in[0];
    const float* o2 = (const float*)d_in[1];
    const int* tgt = (const int*)d_in[2];

    const int B = in_sizes[2];            // 8192
    const int D = in_sizes[0] / B;        // 4096

    float* row_loss = (float*)d_ws;       // B floats = 32 KiB scratch
    float* out = (float*)d_out;

    const int grid = (B + WAVES_PER_BLOCK - 1) / WAVES_PER_BLOCK;
    contrastive_row_loss<<<grid, BLOCK, 0, stream>>>(o1, o2, tgt, row_loss, B, D);
    reduce_mean<<<1, BLOCK, 0, stream>>>(row_loss, out, B);
}